// Round 15
// baseline (416.302 us; speedup 1.0000x reference)
//
#include <hip/hip_runtime.h>
#include <hip/hip_bf16.h>

#define N_ 20000
#define E_ 320000
#define B_ 64

typedef __attribute__((ext_vector_type(8))) short short8;
typedef __attribute__((ext_vector_type(4))) float f4;
typedef __attribute__((ext_vector_type(2))) float f2v;
typedef __attribute__((ext_vector_type(4))) unsigned int u4;
typedef __attribute__((ext_vector_type(4))) unsigned short us4;

union U8 { short s[8]; unsigned short us[8]; short8 v; u4 u; };
union F4 { f4 v; f2v h[2]; float f[4]; };

__device__ __forceinline__ float bs2f(unsigned short s) {
    return __uint_as_float(((unsigned int)s) << 16);
}
__device__ __forceinline__ unsigned short f2bs(float f) {
    unsigned int u = __float_as_uint(f);
    unsigned int r = u + 0x7FFFu + ((u >> 16) & 1u);  // round-to-nearest-even
    return (unsigned short)(r >> 16);
}
// packed f32x2 -> bf16x2 (v_cvt_pk_bf16_f32 on gfx950), low short = a
__device__ __forceinline__ unsigned int pk2(float a, float b) {
    __hip_bfloat162 h = __float22bfloat162_rn(make_float2(a, b));
    union { __hip_bfloat162 h2; unsigned int u; } cv;
    cv.h2 = h;
    return cv.u;
}

// wave-local LDS drain: s_h/s_x are per-wave buffers, no block barrier needed
#define WAVE_LDS_WAIT() asm volatile("s_waitcnt lgkmcnt(0)" ::: "memory")

#define MFMA_B16(a, b, c) __builtin_amdgcn_mfma_f32_16x16x32_bf16(a, b, c, 0, 0, 0)

__device__ __constant__ int c_IDX[36] = {
    0,1,2,3,4,5, 1,6,7,8,9,10, 2,7,11,12,13,14,
    3,8,12,15,16,17, 4,9,13,16,18,19, 5,10,14,17,19,20};

// ====== fused setup: init x/xb (f4) | edge_prep + deg hist | repack w3 | repack w1/w2 | batch hist ======
// deg/bcnt must be zeroed (hipMemsetAsync) BEFORE this kernel.
__global__ __launch_bounds__(256) void k_setup(
    const float* __restrict__ na, const float* __restrict__ eW, const float* __restrict__ eb,
    float* __restrict__ x, unsigned short* __restrict__ xb,
    int* __restrict__ deg, int* __restrict__ bcnt,
    const float* __restrict__ pos, const float* __restrict__ shifts, const float* __restrict__ eattr,
    const int* __restrict__ eidx, unsigned short* __restrict__ efp,
    const float* __restrict__ w3, unsigned short* __restrict__ w3r,
    const float* __restrict__ w1, const float* __restrict__ w2,
    unsigned short* __restrict__ w1r, unsigned short* __restrict__ w2r,
    const int* __restrict__ batch) {
    int bid = blockIdx.x, t = threadIdx.x;
    if (bid < 625) {
        int tid = bid * 256 + t;          // < 160000 exact
        int base = tid * 4;
        int n = tid >> 3, c = (tid & 7) * 4;
        float nv = na[n];
        F4 o;
        for (int r = 0; r < 4; ++r) o.f[r] = nv * eW[c + r] + eb[c + r];
        *(f4*)(x + base) = o.v;
        uint2 pb;
        pb.x = pk2(o.f[0], o.f[1]);
        pb.y = pk2(o.f[2], o.f[3]);
        *(uint2*)(xb + base) = pb;
    } else if (bid < 1875) {
        int e = (bid - 625) * 256 + t;    // < E_ exact
        int s = eidx[e], d = eidx[E_ + e];
        float vx = pos[d * 3 + 0] - pos[s * 3 + 0] + shifts[e * 3 + 0];
        float vy = pos[d * 3 + 1] - pos[s * 3 + 1] + shifts[e * 3 + 1];
        float vz = pos[d * 3 + 2] - pos[s * 3 + 2] + shifts[e * 3 + 2];
        float ln = sqrtf(vx * vx + vy * vy + vz * vz);
        u4 o;
        o[0] = pk2(vx, vy);
        o[1] = pk2(vz, ln);
        o[2] = pk2(eattr[e], 0.f);
        o[3] = 0u;
        *(u4*)(efp + (size_t)e * 8) = o;
        atomicAdd(&deg[d], 1);            // node histogram fused here
    } else if (bid < 1923) {
        int tid = (bid - 1875) * 256 + t; // < 12288 exact
        int l = tid & 63, t2 = (tid >> 6) & 63, i = tid >> 12;
        int q = l >> 4, m = l & 15;
        U8 o;
        for (int j = 0; j < 8; ++j) {
            int k = q * 8 + j;
            o.us[j] = f2bs(w3[(i * 32 + k) * 1024 + t2 * 16 + m]);
        }
        *(u4*)(w3r + (size_t)tid * 8) = o.u;
    } else if (bid < 1926) {
        int tid = (bid - 1923) * 256 + t; // < 768 exact
        bool isw2 = tid >= 384;
        int idx = isw2 ? tid - 384 : tid;
        int i = idx >> 7;                 // layer
        int tau = (idx >> 6) & 1;
        int l = idx & 63;
        int q = l >> 4, m = l & 15;
        U8 o;
        for (int j = 0; j < 8; ++j) {
            int k = q * 8 + j;
            if (!isw2) o.us[j] = (k < 5) ? f2bs(w1[i * 160 + k * 32 + tau * 16 + m]) : (unsigned short)0;
            else       o.us[j] = f2bs(w2[i * 1024 + k * 32 + tau * 16 + m]);
        }
        unsigned short* dst = (isw2 ? w2r : w1r) + i * 1024 + tau * 512 + l * 8;
        *(u4*)dst = o.u;
    } else {
        __shared__ int s[64];
        if (t < 64) s[t] = 0;
        __syncthreads();
        int n = (bid - 1926) * 256 + t;
        if (n < N_) atomicAdd(&s[batch[n]], 1);
        __syncthreads();
        if (t < 64 && s[t]) atomicAdd(&bcnt[t], s[t]);
    }
}

// ================= fused scans (shfl-based, 2 barriers) =================
__global__ __launch_bounds__(1024) void k_scans(const int* __restrict__ deg,
                                                int* __restrict__ off, int* __restrict__ cur,
                                                const int* __restrict__ bcnt,
                                                int* __restrict__ boff, int* __restrict__ bcur) {
    int t = threadIdx.x;
    if (blockIdx.x == 0) {
        __shared__ int shW[16];
        int base = t * 20;  // 1024*20 >= N_
        int loc[20]; int s = 0;
        for (int k = 0; k < 20; ++k) {
            int i = base + k;
            int v = (i < N_) ? deg[i] : 0;
            loc[k] = s; s += v;
        }
        int lane = t & 63, wv = t >> 6;
        int v = s;
        for (int d = 1; d < 64; d <<= 1) {
            int u = __shfl_up(v, d);
            if (lane >= d) v += u;
        }
        if (lane == 63) shW[wv] = v;
        __syncthreads();
        if (wv == 0) {
            int w = (lane < 16) ? shW[lane] : 0;
            for (int d = 1; d < 16; d <<= 1) {
                int u = __shfl_up(w, d);
                if (lane >= d) w += u;
            }
            if (lane < 16) shW[lane] = w;
        }
        __syncthreads();
        int woff = (wv > 0) ? shW[wv - 1] : 0;
        int incl = v + woff;
        int excl = incl - s;
        for (int k = 0; k < 20; ++k) {
            int i = base + k;
            if (i < N_) { int o = excl + loc[k]; off[i] = o; cur[i] = o; }
        }
        if (t == 1023) off[N_] = incl;
    } else {
        if (t < 64) {
            int v0 = bcnt[t];
            int v = v0;
            for (int d = 1; d < 64; d <<= 1) {
                int u = __shfl_up(v, d);
                if (t >= d) v += u;
            }
            boff[t] = v - v0; bcur[t] = v - v0;
            if (t == 63) boff[64] = v;
        }
    }
}

// ================= fused fills: rank[e]=slot (node CSR) + bperm (batch CSR) =================
__global__ __launch_bounds__(256) void k_fills(const int* __restrict__ eidx,
                                               int* __restrict__ cur, int* __restrict__ rank,
                                               const int* __restrict__ batch,
                                               int* __restrict__ bcur, int* __restrict__ bperm) {
    int bid = blockIdx.x, t = threadIdx.x;
    if (bid < 1250) {
        int e = bid * 256 + t;
        rank[e] = atomicAdd(&cur[eidx[E_ + e]], 1);
    } else {
        int n = (bid - 1250) * 256 + t;
        if (n < N_) {
            int p = atomicAdd(&bcur[batch[n]], 1);
            bperm[p] = n;
        }
    }
}

// ================= main edge kernel: 64 edges/wave, 2-wave (128-thread) blocks =================
// LDS: 4096 (s_b3) + 2*1280 (s_h) + 2*5120 (s_x) = 16896B -> 9 blocks/CU; grid 2500 queues/backfills
template <bool STORE>
__global__ __launch_bounds__(128, 4) void k_edge(
    const unsigned short* __restrict__ efp, const int* __restrict__ eidx,
    const int* __restrict__ rank,
    const unsigned short* __restrict__ xb, float* __restrict__ agg, unsigned short* __restrict__ msg,
    const unsigned short* __restrict__ w1r, const float* __restrict__ b1,
    const unsigned short* __restrict__ w2r, const float* __restrict__ b2,
    const unsigned short* __restrict__ w3r, const float* __restrict__ b3) {
    __shared__ float s_b3[1024];                            // 4 KB (block-shared)
    __shared__ __align__(16) unsigned short s_h[2][640];    // per-wave transpose buf, stride 40
    __shared__ __align__(16) unsigned short s_x[2][4][640]; // per-wave bf16 x tiles, stride 40

    const int t = threadIdx.x;
    for (int k = t; k < 1024; k += 128) s_b3[k] = b3[k];

    const int wave = t >> 6, lane = t & 63;
    const int q = lane >> 4, e = lane & 15;
    const int ebase = (blockIdx.x * 2 + wave) * 64;

    // stage x[src] tiles from bf16 mirror: one u4 (16B) load + one 16B LDS store per lane
    for (int g = 0; g < 4; ++g) {
        int srce = eidx[ebase + g * 16 + e];
        u4 P = *(const u4*)(xb + srce * 32 + q * 8);
        *(u4*)&s_x[wave][g][e * 40 + q * 8] = P;  // byte offset e*80+q*16, 16B-aligned
    }

    // loop-invariant W1^T / W2^T fragments (pre-repacked) + bias regs
    U8 w1f[2], w2f[2];
    float b1v[2][4], b2v[2][4];
    for (int tau = 0; tau < 2; ++tau) {
        w1f[tau].u = *(const u4*)(w1r + tau * 512 + lane * 8);
        w2f[tau].u = *(const u4*)(w2r + tau * 512 + lane * 8);
        for (int r = 0; r < 4; ++r) {
            b1v[tau][r] = b1[tau * 16 + q * 4 + r];
            b2v[tau][r] = b2[tau * 16 + q * 4 + r];
        }
    }

    const f4 z4 = {0.f, 0.f, 0.f, 0.f};
    const f2v z2 = {0.f, 0.f};
    short8 h2f[4];

    // per-g MLP: within-wave LDS traffic only -> wave-local waits
    for (int g = 0; g < 4; ++g) {
        U8 ef;
        if (q == 0) ef.u = *(const u4*)(efp + (size_t)(ebase + g * 16 + e) * 8);
        else { u4 zz = {0u, 0u, 0u, 0u}; ef.u = zz; }

        f4 c0 = MFMA_B16(w1f[0].v, ef.v, z4);
        f4 c1 = MFMA_B16(w1f[1].v, ef.v, z4);
        uint2 pkw;
        pkw.x = pk2(fmaxf(c0[0] + b1v[0][0], 0.f), fmaxf(c0[1] + b1v[0][1], 0.f));
        pkw.y = pk2(fmaxf(c0[2] + b1v[0][2], 0.f), fmaxf(c0[3] + b1v[0][3], 0.f));
        *(uint2*)&s_h[wave][e * 40 + q * 4] = pkw;
        pkw.x = pk2(fmaxf(c1[0] + b1v[1][0], 0.f), fmaxf(c1[1] + b1v[1][1], 0.f));
        pkw.y = pk2(fmaxf(c1[2] + b1v[1][2], 0.f), fmaxf(c1[3] + b1v[1][3], 0.f));
        *(uint2*)&s_h[wave][e * 40 + 16 + q * 4] = pkw;
        WAVE_LDS_WAIT();
        short8 h1f = *(const short8*)&s_h[wave][e * 40 + q * 8];
        c0 = MFMA_B16(w2f[0].v, h1f, z4);
        c1 = MFMA_B16(w2f[1].v, h1f, z4);
        pkw.x = pk2(fmaxf(c0[0] + b2v[0][0], 0.f), fmaxf(c0[1] + b2v[0][1], 0.f));
        pkw.y = pk2(fmaxf(c0[2] + b2v[0][2], 0.f), fmaxf(c0[3] + b2v[0][3], 0.f));
        *(uint2*)&s_h[wave][e * 40 + q * 4] = pkw;
        pkw.x = pk2(fmaxf(c1[0] + b2v[1][0], 0.f), fmaxf(c1[1] + b2v[1][1], 0.f));
        pkw.y = pk2(fmaxf(c1[2] + b2v[1][2], 0.f), fmaxf(c1[3] + b2v[1][3], 0.f));
        *(uint2*)&s_h[wave][e * 40 + 16 + q * 4] = pkw;
        WAVE_LDS_WAIT();
        h2f[g] = *(const short8*)&s_h[wave][e * 40 + q * 8];
        WAVE_LDS_WAIT();
    }

    __syncthreads();  // s_b3 visibility

    F4 macc[4][2];
    for (int g = 0; g < 4; ++g) { macc[g][0].v = z4; macc[g][1].v = z4; }

#pragma unroll 4
    for (int h = 0; h < 32; ++h) {
        short8 a0 = *(const short8*)(w3r + h * 1024 + lane * 8);
        short8 a1 = *(const short8*)(w3r + h * 1024 + 512 + lane * 8);
        f4 ci0 = *(const f4*)&s_b3[h * 32 + q * 4];
        f4 ci1 = *(const f4*)&s_b3[h * 32 + 16 + q * 4];
        for (int g = 0; g < 4; ++g) {
            float xv = bs2f(s_x[wave][g][e * 40 + h]);
            F4 d0, d1, m0, m1;
            d0.v = MFMA_B16(a0, h2f[g], ci0);
            d1.v = MFMA_B16(a1, h2f[g], ci1);
            m0.h[0] = __builtin_elementwise_max(d0.h[0], z2);   // v_pk_max_f32
            m0.h[1] = __builtin_elementwise_max(d0.h[1], z2);
            m1.h[0] = __builtin_elementwise_max(d1.h[0], z2);
            m1.h[1] = __builtin_elementwise_max(d1.h[1], z2);
            f2v xv2 = {xv, xv};
            macc[g][0].h[0] = __builtin_elementwise_fma(m0.h[0], xv2, macc[g][0].h[0]);
            macc[g][0].h[1] = __builtin_elementwise_fma(m0.h[1], xv2, macc[g][0].h[1]);
            macc[g][1].h[0] = __builtin_elementwise_fma(m1.h[0], xv2, macc[g][1].h[0]);
            macc[g][1].h[1] = __builtin_elementwise_fma(m1.h[1], xv2, macc[g][1].h[1]);
        }
    }

    if (STORE) {
        for (int g = 0; g < 4; ++g) {
            int rk = rank[ebase + g * 16 + e];
            unsigned short* mp = msg + (size_t)rk * 32 + q * 4;
            for (int p = 0; p < 2; ++p) {
                uint2 m;
                m.x = pk2(macc[g][p].f[0], macc[g][p].f[1]);
                m.y = pk2(macc[g][p].f[2], macc[g][p].f[3]);
                *(uint2*)(mp + p * 16) = m;
            }
        }
    } else {
        for (int g = 0; g < 4; ++g) {
            int dste = eidx[E_ + ebase + g * 16 + e];
            float* ap = agg + dste * 32 + q * 4;
            for (int p = 0; p < 2; ++p)
                for (int r = 0; r < 4; ++r)
                    atomicAdd(ap + p * 16 + r, macc[g][p].f[r]);
        }
    }
}

// ================= gather: one wave per node, contiguous u4 streaming; maintains xb =================
__global__ __launch_bounds__(256) void k_gather(const unsigned short* __restrict__ msg,
                                                const int* __restrict__ off,
                                                const float* __restrict__ cb,
                                                float* __restrict__ x,
                                                unsigned short* __restrict__ xb) {
    int wave = threadIdx.x >> 6, lane = threadIdx.x & 63;
    int n = blockIdx.x * 4 + wave;
    if (n >= N_) return;
    int j0 = off[n], j1 = off[n + 1];
    const unsigned short* base = msg + (size_t)j0 * 32;
    int nchunk = (j1 - j0) * 4;  // 16B chunks; row=64B so always whole chunks
    float a[8] = {0.f, 0.f, 0.f, 0.f, 0.f, 0.f, 0.f, 0.f};
    for (int it = lane; it < nchunk; it += 64) {
        u4 v = *(const u4*)(base + it * 8);
        for (int m = 0; m < 4; ++m) {
            unsigned int w = v[m];
            a[2 * m]     += __uint_as_float(w << 16);
            a[2 * m + 1] += __uint_as_float(w & 0xffff0000u);
        }
    }
    for (int d = 4; d < 64; d <<= 1)
        for (int m = 0; m < 8; ++m)
            a[m] += __shfl_xor(a[m], d);
    if (lane < 4) {
        int c0 = lane * 8;
        float* xp = x + n * 32 + c0;
        F4 xa, xb2;
        xa.v = *(const f4*)xp;
        xb2.v = *(const f4*)(xp + 4);
        for (int i = 0; i < 4; ++i) {
            xa.f[i]  += fmaxf(a[i] + cb[c0 + i], 0.f);
            xb2.f[i] += fmaxf(a[4 + i] + cb[c0 + 4 + i], 0.f);
        }
        *(f4*)xp = xa.v;
        *(f4*)(xp + 4) = xb2.v;
        u4 P;
        P[0] = pk2(xa.f[0], xa.f[1]);
        P[1] = pk2(xa.f[2], xa.f[3]);
        P[2] = pk2(xb2.f[0], xb2.f[1]);
        P[3] = pk2(xb2.f[2], xb2.f[3]);
        *(u4*)(xb + n * 32 + c0) = P;
    }
}

__device__ __forceinline__ float selu_(float v) {
    return 1.0507009873554805f * (v > 0.f ? v : 1.6732632423543772f * (expf(v) - 1.f));
}

// ================= fused pooling (32 slots) + head MLP + IDX gather =================
__global__ __launch_bounds__(1024) void k_pool_head(const float* __restrict__ x,
                                                    const int* __restrict__ boff,
                                                    const int* __restrict__ bperm,
                                                    const float* __restrict__ W1, const float* __restrict__ b1,
                                                    const float* __restrict__ W2, const float* __restrict__ b2,
                                                    const float* __restrict__ W3, const float* __restrict__ b3,
                                                    const float* __restrict__ W4, const float* __restrict__ b4,
                                                    float* __restrict__ out) {
    __shared__ float sp[32][32];
    __shared__ float s0[32], s1[128], s2[64], s3[32], s4[21];
    int b = blockIdx.x, t = threadIdx.x, c = t & 31, slot = t >> 5;
    int j0 = boff[b], j1 = boff[b + 1];
    float a = 0.f;
    for (int j = j0 + slot; j < j1; j += 32)
        a += x[bperm[j] * 32 + c];
    sp[slot][c] = a;
    __syncthreads();
    if (t < 32) {
        float s = 0.f;
        for (int k = 0; k < 32; ++k) s += sp[k][t];
        s0[t] = s / fmaxf((float)(j1 - j0), 1.f);
    }
    __syncthreads();
    if (t < 128) {
        float v = b1[t];
        for (int cc = 0; cc < 32; ++cc) v += s0[cc] * W1[cc * 128 + t];
        s1[t] = selu_(v);
    }
    __syncthreads();
    if (t < 64) {
        float v = b2[t];
        for (int cc = 0; cc < 128; ++cc) v += s1[cc] * W2[cc * 64 + t];
        s2[t] = selu_(v);
    }
    __syncthreads();
    if (t < 32) {
        float v = b3[t];
        for (int cc = 0; cc < 64; ++cc) v += s2[cc] * W3[cc * 32 + t];
        s3[t] = selu_(v);
    }
    __syncthreads();
    if (t < 21) {
        float v = b4[t];
        for (int cc = 0; cc < 32; ++cc) v += s3[cc] * W4[cc * 21 + t];
        s4[t] = v;
    }
    __syncthreads();
    if (t < 36) out[b * 36 + t] = s4[c_IDX[t]];
}

// ================= fallback helpers (atomic path) =================
__global__ __launch_bounds__(256) void k_init_fb(const float* __restrict__ na,
                                                 const float* __restrict__ eW,
                                                 const float* __restrict__ eb,
                                                 float* __restrict__ x, unsigned short* __restrict__ xb,
                                                 float* __restrict__ agg) {
    int tid = blockIdx.x * 256 + threadIdx.x;
    int n = tid >> 5, c = tid & 31;
    float v = na[n] * eW[c] + eb[c];
    x[tid] = v;
    xb[tid] = f2bs(v);
    agg[tid] = 0.f;
}

__global__ __launch_bounds__(256) void k_prep_fb(const float* __restrict__ pos,
                                                 const float* __restrict__ shifts,
                                                 const float* __restrict__ eattr,
                                                 const int* __restrict__ eidx,
                                                 unsigned short* __restrict__ efp) {
    int e = blockIdx.x * 256 + threadIdx.x;
    int s = eidx[e], d = eidx[E_ + e];
    float vx = pos[d * 3 + 0] - pos[s * 3 + 0] + shifts[e * 3 + 0];
    float vy = pos[d * 3 + 1] - pos[s * 3 + 1] + shifts[e * 3 + 1];
    float vz = pos[d * 3 + 2] - pos[s * 3 + 2] + shifts[e * 3 + 2];
    float ln = sqrtf(vx * vx + vy * vy + vz * vz);
    u4 o;
    o[0] = pk2(vx, vy);
    o[1] = pk2(vz, ln);
    o[2] = pk2(eattr[e], 0.f);
    o[3] = 0u;
    *(u4*)(efp + (size_t)e * 8) = o;
}

__global__ __launch_bounds__(256) void k_repack_fb(const float* __restrict__ w3,
                                                   unsigned short* __restrict__ w3r,
                                                   const float* __restrict__ w1,
                                                   const float* __restrict__ w2,
                                                   unsigned short* __restrict__ w1r,
                                                   unsigned short* __restrict__ w2r) {
    int tid = blockIdx.x * 256 + threadIdx.x;
    if (tid < 12288) {
        int l = tid & 63, t2 = (tid >> 6) & 63, i = tid >> 12;
        int q = l >> 4, m = l & 15;
        U8 o;
        for (int j = 0; j < 8; ++j) {
            int k = q * 8 + j;
            o.us[j] = f2bs(w3[(i * 32 + k) * 1024 + t2 * 16 + m]);
        }
        *(u4*)(w3r + (size_t)tid * 8) = o.u;
    } else if (tid < 13056) {
        int t2 = tid - 12288;
        bool isw2 = t2 >= 384;
        int idx = isw2 ? t2 - 384 : t2;
        int i = idx >> 7, tau = (idx >> 6) & 1, l = idx & 63;
        int q = l >> 4, m = l & 15;
        U8 o;
        for (int j = 0; j < 8; ++j) {
            int k = q * 8 + j;
            if (!isw2) o.us[j] = (k < 5) ? f2bs(w1[i * 160 + k * 32 + tau * 16 + m]) : (unsigned short)0;
            else       o.us[j] = f2bs(w2[i * 1024 + k * 32 + tau * 16 + m]);
        }
        unsigned short* dst = (isw2 ? w2r : w1r) + i * 1024 + tau * 512 + l * 8;
        *(u4*)dst = o.u;
    }
}

__global__ __launch_bounds__(256) void k_node(float* __restrict__ x, unsigned short* __restrict__ xb,
                                              float* __restrict__ agg, const float* __restrict__ cb) {
    int tid = blockIdx.x * 256 + threadIdx.x;
    int c = tid & 31;
    float a = agg[tid] + cb[c];
    float v = x[tid] + fmaxf(a, 0.f);
    x[tid] = v;
    xb[tid] = f2bs(v);
    agg[tid] = 0.f;
}

__global__ __launch_bounds__(256) void k_zero_pool(float* __restrict__ pooled, int* __restrict__ cnt) {
    int tid = blockIdx.x * 256 + threadIdx.x;
    if (tid < 2048) pooled[tid] = 0.f;
    else if (tid < 2112) cnt[tid - 2048] = 0;
}

__global__ __launch_bounds__(256) void k_pool(const float* __restrict__ x, const int* __restrict__ batch,
                                              float* __restrict__ pooled, int* __restrict__ cnt) {
    int tid = blockIdx.x * 256 + threadIdx.x;
    int n = tid >> 5, c = tid & 31;
    int b = batch[n];
    atomicAdd(&pooled[b * 32 + c], x[tid]);
    if (c == 0) atomicAdd(&cnt[b], 1);
}

__global__ __launch_bounds__(128) void k_head(const float* __restrict__ pooled, const int* __restrict__ cnt,
                                              const float* __restrict__ W1, const float* __restrict__ b1,
                                              const float* __restrict__ W2, const float* __restrict__ b2,
                                              const float* __restrict__ W3, const float* __restrict__ b3,
                                              const float* __restrict__ W4, const float* __restrict__ b4,
                                              float* __restrict__ out) {
    __shared__ float s0[32], s1[128], s2[64], s3[32], s4[21];
    int b = blockIdx.x, t = threadIdx.x;
    if (t < 32) s0[t] = pooled[b * 32 + t] / fmaxf((float)cnt[b], 1.f);
    __syncthreads();
    {
        float a = b1[t];
        for (int c = 0; c < 32; ++c) a += s0[c] * W1[c * 128 + t];
        s1[t] = selu_(a);
    }
    __syncthreads();
    if (t < 64) {
        float a = b2[t];
        for (int c = 0; c < 128; ++c) a += s1[c] * W2[c * 64 + t];
        s2[t] = selu_(a);
    }
    __syncthreads();
    if (t < 32) {
        float a = b3[t];
        for (int c = 0; c < 64; ++c) a += s2[c] * W3[c * 32 + t];
        s3[t] = selu_(a);
    }
    __syncthreads();
    if (t < 21) {
        float a = b4[t];
        for (int c = 0; c < 32; ++c) a += s3[c] * W4[c * 21 + t];
        s4[t] = a;
    }
    __syncthreads();
    if (t < 36) out[b * 36 + t] = s4[c_IDX[t]];
}

extern "C" void kernel_launch(void* const* d_in, const int* in_sizes, int n_in,
                              void* d_out, int out_size, void* d_ws, size_t ws_size,
                              hipStream_t stream) {
    const float* na     = (const float*)d_in[0];
    const float* pos    = (const float*)d_in[1];
    const float* shifts = (const float*)d_in[2];
    const float* eattr  = (const float*)d_in[3];
    const int*   eidx   = (const int*)d_in[4];
    const int*   batch  = (const int*)d_in[5];
    const float* embW   = (const float*)d_in[6];
    const float* embB   = (const float*)d_in[7];
    const float* eW1    = (const float*)d_in[8];
    const float* eb1    = (const float*)d_in[9];
    const float* eW2    = (const float*)d_in[10];
    const float* eb2    = (const float*)d_in[11];
    const float* eW3    = (const float*)d_in[12];
    const float* eb3    = (const float*)d_in[13];
    const float* cvb    = (const float*)d_in[14];
    const float* hW1    = (const float*)d_in[15];
    const float* hb1    = (const float*)d_in[16];
    const float* hW2    = (const float*)d_in[17];
    const float* hb2    = (const float*)d_in[18];
    const float* hW3    = (const float*)d_in[19];
    const float* hb3    = (const float*)d_in[20];
    const float* hW4    = (const float*)d_in[21];
    const float* hb4    = (const float*)d_in[22];

    // layout: x | xb | deg | bcnt | off | cur | rank | boff | bcur | bperm | efp | w3r | w1r | w2r | msg
    const size_t need_csr = (size_t)640000 * 4 + (size_t)640000 * 2
                          + (size_t)(20000 + 64 + 20004 + 20000 + 320000 + 68 + 64 + 20000) * 4
                          + ((size_t)E_ * 8 + 98304 + 3072 + 3072 + (size_t)E_ * 32) * 2;

    if (ws_size >= need_csr) {
        char* ws = (char*)d_ws;
        float* x            = (float*)ws;                        // 640000 f32
        unsigned short* xb  = (unsigned short*)(x + 640000);     // 640000 bf16
        int*   deg    = (int*)(xb + 640000);                     // 20000
        int*   bcnt   = deg + 20000;                             // 64 (contiguous with deg)
        int*   off    = bcnt + 64;                               // 20001 (pad 20004)
        int*   cur    = off + 20004;                             // 20000
        int*   rank   = cur + 20000;                             // 320000
        int*   boff   = rank + 320000;                           // 65 (pad 68)
        int*   bcur   = boff + 68;                               // 64
        int*   bperm  = bcur + 64;                               // 20000
        unsigned short* efp = (unsigned short*)(bperm + 20000);  // E_*8 bf16
        unsigned short* w3r = efp + (size_t)E_ * 8;              // 98304 bf16
        unsigned short* w1r = w3r + 98304;                       // 3072 bf16
        unsigned short* w2r = w1r + 3072;                        // 3072 bf16
        unsigned short* msg = w2r + 3072;                        // E_*32 bf16

        hipMemsetAsync(deg, 0, (20000 + 64) * sizeof(int), stream);  // deg + bcnt
        k_setup<<<2005, 256, 0, stream>>>(na, embW, embB, x, xb, deg, bcnt,
                                          pos, shifts, eattr, eidx, efp,
                                          eW3, w3r, eW1, eW2, w1r, w2r, batch);
        k_scans<<<2, 1024, 0, stream>>>(deg, off, cur, bcnt, boff, bcur);
        k_fills<<<1329, 256, 0, stream>>>(eidx, cur, rank, batch, bcur, bperm);

        for (int i = 0; i < 3; ++i) {
            k_edge<true><<<2500, 128, 0, stream>>>(efp, eidx, rank, xb, nullptr, msg,
                                                   w1r + i * 1024, eb1 + i * 32,
                                                   w2r + i * 1024, eb2 + i * 32,
                                                   w3r + i * 32768, eb3 + i * 1024);
            k_gather<<<5000, 256, 0, stream>>>(msg, off, cvb + i * 32, x, xb);
        }

        k_pool_head<<<64, 1024, 0, stream>>>(x, boff, bperm,
                                             hW1, hb1, hW2, hb2, hW3, hb3, hW4, hb4,
                                             (float*)d_out);
    } else {
        // fallback: atomic scatter path
        char* ws = (char*)d_ws;
        float* x           = (float*)ws;                      // 640000 f32
        unsigned short* xb = (unsigned short*)(x + 640000);   // 640000 bf16
        float* agg    = (float*)(xb + 640000);                // 640000 f32
        float* pooled = agg + 640000;                         // 2048 f32
        int*   cnt    = (int*)(pooled + 2048);                // 64
        unsigned short* efp = (unsigned short*)(cnt + 64);    // E_*8 bf16
        unsigned short* w3r = efp + (size_t)E_ * 8;           // 98304 bf16
        unsigned short* w1r = w3r + 98304;                    // 3072
        unsigned short* w2r = w1r + 3072;                     // 3072

        k_init_fb<<<2500, 256, 0, stream>>>(na, embW, embB, x, xb, agg);
        k_prep_fb<<<1250, 256, 0, stream>>>(pos, shifts, eattr, eidx, efp);
        k_repack_fb<<<51, 256, 0, stream>>>(eW3, w3r, eW1, eW2, w1r, w2r);
        k_zero_pool<<<9, 256, 0, stream>>>(pooled, cnt);

        for (int i = 0; i < 3; ++i) {
            k_edge<false><<<2500, 128, 0, stream>>>(efp, eidx, nullptr, xb, agg, nullptr,
                                                    w1r + i * 1024, eb1 + i * 32,
                                                    w2r + i * 1024, eb2 + i * 32,
                                                    w3r + i * 32768, eb3 + i * 1024);
            k_node<<<2500, 256, 0, stream>>>(x, xb, agg, cvb + i * 32);
        }

        k_pool<<<2500, 256, 0, stream>>>(x, batch, pooled, cnt);
        k_head<<<64, 128, 0, stream>>>(pooled, cnt, hW1, hb1, hW2, hb2, hW3, hb3, hW4, hb4,
                                       (float*)d_out);
    }
}

// Round 16
// 361.660 us; speedup vs baseline: 1.1511x; 1.1511x over previous
//
#include <hip/hip_runtime.h>
#include <hip/hip_bf16.h>

#define N_ 20000
#define E_ 320000
#define B_ 64

typedef __attribute__((ext_vector_type(8))) short short8;
typedef __attribute__((ext_vector_type(4))) float f4;
typedef __attribute__((ext_vector_type(2))) float f2v;
typedef __attribute__((ext_vector_type(4))) unsigned int u4;
typedef __attribute__((ext_vector_type(4))) unsigned short us4;

union U8 { short s[8]; unsigned short us[8]; short8 v; u4 u; };
union F4 { f4 v; f2v h[2]; float f[4]; };

__device__ __forceinline__ float bs2f(unsigned short s) {
    return __uint_as_float(((unsigned int)s) << 16);
}
__device__ __forceinline__ unsigned short f2bs(float f) {
    unsigned int u = __float_as_uint(f);
    unsigned int r = u + 0x7FFFu + ((u >> 16) & 1u);  // round-to-nearest-even
    return (unsigned short)(r >> 16);
}
// packed f32x2 -> bf16x2 (v_cvt_pk_bf16_f32 on gfx950), low short = a
__device__ __forceinline__ unsigned int pk2(float a, float b) {
    __hip_bfloat162 h = __float22bfloat162_rn(make_float2(a, b));
    union { __hip_bfloat162 h2; unsigned int u; } cv;
    cv.h2 = h;
    return cv.u;
}

// wave-local LDS drain: s_h/s_x are per-wave buffers, no block barrier needed
#define WAVE_LDS_WAIT() asm volatile("s_waitcnt lgkmcnt(0)" ::: "memory")

#define MFMA_B16(a, b, c) __builtin_amdgcn_mfma_f32_16x16x32_bf16(a, b, c, 0, 0, 0)

__device__ __constant__ int c_IDX[36] = {
    0,1,2,3,4,5, 1,6,7,8,9,10, 2,7,11,12,13,14,
    3,8,12,15,16,17, 4,9,13,16,18,19, 5,10,14,17,19,20};

// ====== fused setup: init x/xb (f4) | edge_prep + deg hist | repack w3 | repack w1/w2 | batch hist ======
// deg/bcnt must be zeroed (hipMemsetAsync) BEFORE this kernel.
__global__ __launch_bounds__(256) void k_setup(
    const float* __restrict__ na, const float* __restrict__ eW, const float* __restrict__ eb,
    float* __restrict__ x, unsigned short* __restrict__ xb,
    int* __restrict__ deg, int* __restrict__ bcnt,
    const float* __restrict__ pos, const float* __restrict__ shifts, const float* __restrict__ eattr,
    const int* __restrict__ eidx, unsigned short* __restrict__ efp,
    const float* __restrict__ w3, unsigned short* __restrict__ w3r,
    const float* __restrict__ w1, const float* __restrict__ w2,
    unsigned short* __restrict__ w1r, unsigned short* __restrict__ w2r,
    const int* __restrict__ batch) {
    int bid = blockIdx.x, t = threadIdx.x;
    if (bid < 625) {
        int tid = bid * 256 + t;          // < 160000 exact
        int base = tid * 4;
        int n = tid >> 3, c = (tid & 7) * 4;
        float nv = na[n];
        F4 o;
        for (int r = 0; r < 4; ++r) o.f[r] = nv * eW[c + r] + eb[c + r];
        *(f4*)(x + base) = o.v;
        uint2 pb;
        pb.x = pk2(o.f[0], o.f[1]);
        pb.y = pk2(o.f[2], o.f[3]);
        *(uint2*)(xb + base) = pb;
    } else if (bid < 1875) {
        int e = (bid - 625) * 256 + t;    // < E_ exact
        int s = eidx[e], d = eidx[E_ + e];
        float vx = pos[d * 3 + 0] - pos[s * 3 + 0] + shifts[e * 3 + 0];
        float vy = pos[d * 3 + 1] - pos[s * 3 + 1] + shifts[e * 3 + 1];
        float vz = pos[d * 3 + 2] - pos[s * 3 + 2] + shifts[e * 3 + 2];
        float ln = sqrtf(vx * vx + vy * vy + vz * vz);
        u4 o;
        o[0] = pk2(vx, vy);
        o[1] = pk2(vz, ln);
        o[2] = pk2(eattr[e], 0.f);
        o[3] = 0u;
        *(u4*)(efp + (size_t)e * 8) = o;
        atomicAdd(&deg[d], 1);            // node histogram fused here
    } else if (bid < 1923) {
        int tid = (bid - 1875) * 256 + t; // < 12288 exact
        int l = tid & 63, t2 = (tid >> 6) & 63, i = tid >> 12;
        int q = l >> 4, m = l & 15;
        U8 o;
        for (int j = 0; j < 8; ++j) {
            int k = q * 8 + j;
            o.us[j] = f2bs(w3[(i * 32 + k) * 1024 + t2 * 16 + m]);
        }
        *(u4*)(w3r + (size_t)tid * 8) = o.u;
    } else if (bid < 1926) {
        int tid = (bid - 1923) * 256 + t; // < 768 exact
        bool isw2 = tid >= 384;
        int idx = isw2 ? tid - 384 : tid;
        int i = idx >> 7;                 // layer
        int tau = (idx >> 6) & 1;
        int l = idx & 63;
        int q = l >> 4, m = l & 15;
        U8 o;
        for (int j = 0; j < 8; ++j) {
            int k = q * 8 + j;
            if (!isw2) o.us[j] = (k < 5) ? f2bs(w1[i * 160 + k * 32 + tau * 16 + m]) : (unsigned short)0;
            else       o.us[j] = f2bs(w2[i * 1024 + k * 32 + tau * 16 + m]);
        }
        unsigned short* dst = (isw2 ? w2r : w1r) + i * 1024 + tau * 512 + l * 8;
        *(u4*)dst = o.u;
    } else {
        __shared__ int s[64];
        if (t < 64) s[t] = 0;
        __syncthreads();
        int n = (bid - 1926) * 256 + t;
        if (n < N_) atomicAdd(&s[batch[n]], 1);
        __syncthreads();
        if (t < 64 && s[t]) atomicAdd(&bcnt[t], s[t]);
    }
}

// ================= fused scans (shfl-based, 2 barriers) =================
__global__ __launch_bounds__(1024) void k_scans(const int* __restrict__ deg,
                                                int* __restrict__ off, int* __restrict__ cur,
                                                const int* __restrict__ bcnt,
                                                int* __restrict__ boff, int* __restrict__ bcur) {
    int t = threadIdx.x;
    if (blockIdx.x == 0) {
        __shared__ int shW[16];
        int base = t * 20;  // 1024*20 >= N_
        int loc[20]; int s = 0;
        for (int k = 0; k < 20; ++k) {
            int i = base + k;
            int v = (i < N_) ? deg[i] : 0;
            loc[k] = s; s += v;
        }
        int lane = t & 63, wv = t >> 6;
        int v = s;
        for (int d = 1; d < 64; d <<= 1) {
            int u = __shfl_up(v, d);
            if (lane >= d) v += u;
        }
        if (lane == 63) shW[wv] = v;
        __syncthreads();
        if (wv == 0) {
            int w = (lane < 16) ? shW[lane] : 0;
            for (int d = 1; d < 16; d <<= 1) {
                int u = __shfl_up(w, d);
                if (lane >= d) w += u;
            }
            if (lane < 16) shW[lane] = w;
        }
        __syncthreads();
        int woff = (wv > 0) ? shW[wv - 1] : 0;
        int incl = v + woff;
        int excl = incl - s;
        for (int k = 0; k < 20; ++k) {
            int i = base + k;
            if (i < N_) { int o = excl + loc[k]; off[i] = o; cur[i] = o; }
        }
        if (t == 1023) off[N_] = incl;
    } else {
        if (t < 64) {
            int v0 = bcnt[t];
            int v = v0;
            for (int d = 1; d < 64; d <<= 1) {
                int u = __shfl_up(v, d);
                if (t >= d) v += u;
            }
            boff[t] = v - v0; bcur[t] = v - v0;
            if (t == 63) boff[64] = v;
        }
    }
}

// ================= fused fills: rank[e]=slot (node CSR) + bperm (batch CSR) =================
__global__ __launch_bounds__(256) void k_fills(const int* __restrict__ eidx,
                                               int* __restrict__ cur, int* __restrict__ rank,
                                               const int* __restrict__ batch,
                                               int* __restrict__ bcur, int* __restrict__ bperm) {
    int bid = blockIdx.x, t = threadIdx.x;
    if (bid < 1250) {
        int e = bid * 256 + t;
        rank[e] = atomicAdd(&cur[eidx[E_ + e]], 1);
    } else {
        int n = (bid - 1250) * 256 + t;
        if (n < N_) {
            int p = atomicAdd(&bcur[batch[n]], 1);
            bperm[p] = n;
        }
    }
}

// ================= main edge kernel: 64 edges/wave, rank-order msg stores (R12-proven) =================
template <bool STORE>
__global__ __launch_bounds__(256, 5) void k_edge(
    const unsigned short* __restrict__ efp, const int* __restrict__ eidx,
    const int* __restrict__ rank,
    const unsigned short* __restrict__ xb, float* __restrict__ agg, unsigned short* __restrict__ msg,
    const unsigned short* __restrict__ w1r, const float* __restrict__ b1,
    const unsigned short* __restrict__ w2r, const float* __restrict__ b2,
    const unsigned short* __restrict__ w3r, const float* __restrict__ b3) {
    __shared__ float s_b3[1024];                            // 4 KB (block-shared)
    __shared__ __align__(16) unsigned short s_h[4][640];    // per-wave transpose buf, stride 40
    __shared__ __align__(16) unsigned short s_x[4][4][640]; // per-wave bf16 x tiles, stride 40

    const int t = threadIdx.x;
    for (int k = t; k < 1024; k += 256) s_b3[k] = b3[k];

    const int wave = t >> 6, lane = t & 63;
    const int q = lane >> 4, e = lane & 15;
    const int ebase = (blockIdx.x * 4 + wave) * 64;

    // stage x[src] tiles from bf16 mirror: one u4 (16B) load + one 16B LDS store per lane
    for (int g = 0; g < 4; ++g) {
        int srce = eidx[ebase + g * 16 + e];
        u4 P = *(const u4*)(xb + srce * 32 + q * 8);
        *(u4*)&s_x[wave][g][e * 40 + q * 8] = P;  // byte offset e*80+q*16, 16B-aligned
    }

    // loop-invariant W1^T / W2^T fragments (pre-repacked) + bias regs
    U8 w1f[2], w2f[2];
    float b1v[2][4], b2v[2][4];
    for (int tau = 0; tau < 2; ++tau) {
        w1f[tau].u = *(const u4*)(w1r + tau * 512 + lane * 8);
        w2f[tau].u = *(const u4*)(w2r + tau * 512 + lane * 8);
        for (int r = 0; r < 4; ++r) {
            b1v[tau][r] = b1[tau * 16 + q * 4 + r];
            b2v[tau][r] = b2[tau * 16 + q * 4 + r];
        }
    }

    const f4 z4 = {0.f, 0.f, 0.f, 0.f};
    const f2v z2 = {0.f, 0.f};
    short8 h2f[4];

    // per-g MLP: within-wave LDS traffic only -> wave-local waits
    for (int g = 0; g < 4; ++g) {
        U8 ef;
        if (q == 0) ef.u = *(const u4*)(efp + (size_t)(ebase + g * 16 + e) * 8);
        else { u4 zz = {0u, 0u, 0u, 0u}; ef.u = zz; }

        f4 c0 = MFMA_B16(w1f[0].v, ef.v, z4);
        f4 c1 = MFMA_B16(w1f[1].v, ef.v, z4);
        uint2 pkw;
        pkw.x = pk2(fmaxf(c0[0] + b1v[0][0], 0.f), fmaxf(c0[1] + b1v[0][1], 0.f));
        pkw.y = pk2(fmaxf(c0[2] + b1v[0][2], 0.f), fmaxf(c0[3] + b1v[0][3], 0.f));
        *(uint2*)&s_h[wave][e * 40 + q * 4] = pkw;
        pkw.x = pk2(fmaxf(c1[0] + b1v[1][0], 0.f), fmaxf(c1[1] + b1v[1][1], 0.f));
        pkw.y = pk2(fmaxf(c1[2] + b1v[1][2], 0.f), fmaxf(c1[3] + b1v[1][3], 0.f));
        *(uint2*)&s_h[wave][e * 40 + 16 + q * 4] = pkw;
        WAVE_LDS_WAIT();
        short8 h1f = *(const short8*)&s_h[wave][e * 40 + q * 8];
        c0 = MFMA_B16(w2f[0].v, h1f, z4);
        c1 = MFMA_B16(w2f[1].v, h1f, z4);
        pkw.x = pk2(fmaxf(c0[0] + b2v[0][0], 0.f), fmaxf(c0[1] + b2v[0][1], 0.f));
        pkw.y = pk2(fmaxf(c0[2] + b2v[0][2], 0.f), fmaxf(c0[3] + b2v[0][3], 0.f));
        *(uint2*)&s_h[wave][e * 40 + q * 4] = pkw;
        pkw.x = pk2(fmaxf(c1[0] + b2v[1][0], 0.f), fmaxf(c1[1] + b2v[1][1], 0.f));
        pkw.y = pk2(fmaxf(c1[2] + b2v[1][2], 0.f), fmaxf(c1[3] + b2v[1][3], 0.f));
        *(uint2*)&s_h[wave][e * 40 + 16 + q * 4] = pkw;
        WAVE_LDS_WAIT();
        h2f[g] = *(const short8*)&s_h[wave][e * 40 + q * 8];
        WAVE_LDS_WAIT();
    }

    __syncthreads();  // s_b3 visibility

    F4 macc[4][2];
    for (int g = 0; g < 4; ++g) { macc[g][0].v = z4; macc[g][1].v = z4; }

#pragma unroll 4
    for (int h = 0; h < 32; ++h) {
        short8 a0 = *(const short8*)(w3r + h * 1024 + lane * 8);
        short8 a1 = *(const short8*)(w3r + h * 1024 + 512 + lane * 8);
        f4 ci0 = *(const f4*)&s_b3[h * 32 + q * 4];
        f4 ci1 = *(const f4*)&s_b3[h * 32 + 16 + q * 4];
        for (int g = 0; g < 4; ++g) {
            float xv = bs2f(s_x[wave][g][e * 40 + h]);
            F4 d0, d1, m0, m1;
            d0.v = MFMA_B16(a0, h2f[g], ci0);
            d1.v = MFMA_B16(a1, h2f[g], ci1);
            m0.h[0] = __builtin_elementwise_max(d0.h[0], z2);   // v_pk_max_f32
            m0.h[1] = __builtin_elementwise_max(d0.h[1], z2);
            m1.h[0] = __builtin_elementwise_max(d1.h[0], z2);
            m1.h[1] = __builtin_elementwise_max(d1.h[1], z2);
            f2v xv2 = {xv, xv};
            macc[g][0].h[0] = __builtin_elementwise_fma(m0.h[0], xv2, macc[g][0].h[0]);
            macc[g][0].h[1] = __builtin_elementwise_fma(m0.h[1], xv2, macc[g][0].h[1]);
            macc[g][1].h[0] = __builtin_elementwise_fma(m1.h[0], xv2, macc[g][1].h[0]);
            macc[g][1].h[1] = __builtin_elementwise_fma(m1.h[1], xv2, macc[g][1].h[1]);
        }
    }

    if (STORE) {
        for (int g = 0; g < 4; ++g) {
            int rk = rank[ebase + g * 16 + e];
            unsigned short* mp = msg + (size_t)rk * 32 + q * 4;
            for (int p = 0; p < 2; ++p) {
                uint2 m;
                m.x = pk2(macc[g][p].f[0], macc[g][p].f[1]);
                m.y = pk2(macc[g][p].f[2], macc[g][p].f[3]);
                *(uint2*)(mp + p * 16) = m;
            }
        }
    } else {
        for (int g = 0; g < 4; ++g) {
            int dste = eidx[E_ + ebase + g * 16 + e];
            float* ap = agg + dste * 32 + q * 4;
            for (int p = 0; p < 2; ++p)
                for (int r = 0; r < 4; ++r)
                    atomicAdd(ap + p * 16 + r, macc[g][p].f[r]);
        }
    }
}

// ================= gather: one wave per node, contiguous u4 streaming; maintains xb =================
__global__ __launch_bounds__(256) void k_gather(const unsigned short* __restrict__ msg,
                                                const int* __restrict__ off,
                                                const float* __restrict__ cb,
                                                float* __restrict__ x,
                                                unsigned short* __restrict__ xb) {
    int wave = threadIdx.x >> 6, lane = threadIdx.x & 63;
    int n = blockIdx.x * 4 + wave;
    if (n >= N_) return;
    int j0 = off[n], j1 = off[n + 1];
    const unsigned short* base = msg + (size_t)j0 * 32;
    int nchunk = (j1 - j0) * 4;  // 16B chunks; row=64B so always whole chunks
    float a[8] = {0.f, 0.f, 0.f, 0.f, 0.f, 0.f, 0.f, 0.f};
    for (int it = lane; it < nchunk; it += 64) {
        u4 v = *(const u4*)(base + it * 8);
        for (int m = 0; m < 4; ++m) {
            unsigned int w = v[m];
            a[2 * m]     += __uint_as_float(w << 16);
            a[2 * m + 1] += __uint_as_float(w & 0xffff0000u);
        }
    }
    for (int d = 4; d < 64; d <<= 1)
        for (int m = 0; m < 8; ++m)
            a[m] += __shfl_xor(a[m], d);
    if (lane < 4) {
        int c0 = lane * 8;
        float* xp = x + n * 32 + c0;
        F4 xa, xb2;
        xa.v = *(const f4*)xp;
        xb2.v = *(const f4*)(xp + 4);
        for (int i = 0; i < 4; ++i) {
            xa.f[i]  += fmaxf(a[i] + cb[c0 + i], 0.f);
            xb2.f[i] += fmaxf(a[4 + i] + cb[c0 + 4 + i], 0.f);
        }
        *(f4*)xp = xa.v;
        *(f4*)(xp + 4) = xb2.v;
        u4 P;
        P[0] = pk2(xa.f[0], xa.f[1]);
        P[1] = pk2(xa.f[2], xa.f[3]);
        P[2] = pk2(xb2.f[0], xb2.f[1]);
        P[3] = pk2(xb2.f[2], xb2.f[3]);
        *(u4*)(xb + n * 32 + c0) = P;
    }
}

__device__ __forceinline__ float selu_(float v) {
    return 1.0507009873554805f * (v > 0.f ? v : 1.6732632423543772f * (expf(v) - 1.f));
}

// ================= fused pooling (32 slots) + head MLP + IDX gather =================
__global__ __launch_bounds__(1024) void k_pool_head(const float* __restrict__ x,
                                                    const int* __restrict__ boff,
                                                    const int* __restrict__ bperm,
                                                    const float* __restrict__ W1, const float* __restrict__ b1,
                                                    const float* __restrict__ W2, const float* __restrict__ b2,
                                                    const float* __restrict__ W3, const float* __restrict__ b3,
                                                    const float* __restrict__ W4, const float* __restrict__ b4,
                                                    float* __restrict__ out) {
    __shared__ float sp[32][32];
    __shared__ float s0[32], s1[128], s2[64], s3[32], s4[21];
    int b = blockIdx.x, t = threadIdx.x, c = t & 31, slot = t >> 5;
    int j0 = boff[b], j1 = boff[b + 1];
    float a = 0.f;
    for (int j = j0 + slot; j < j1; j += 32)
        a += x[bperm[j] * 32 + c];
    sp[slot][c] = a;
    __syncthreads();
    if (t < 32) {
        float s = 0.f;
        for (int k = 0; k < 32; ++k) s += sp[k][t];
        s0[t] = s / fmaxf((float)(j1 - j0), 1.f);
    }
    __syncthreads();
    if (t < 128) {
        float v = b1[t];
        for (int cc = 0; cc < 32; ++cc) v += s0[cc] * W1[cc * 128 + t];
        s1[t] = selu_(v);
    }
    __syncthreads();
    if (t < 64) {
        float v = b2[t];
        for (int cc = 0; cc < 128; ++cc) v += s1[cc] * W2[cc * 64 + t];
        s2[t] = selu_(v);
    }
    __syncthreads();
    if (t < 32) {
        float v = b3[t];
        for (int cc = 0; cc < 64; ++cc) v += s2[cc] * W3[cc * 32 + t];
        s3[t] = selu_(v);
    }
    __syncthreads();
    if (t < 21) {
        float v = b4[t];
        for (int cc = 0; cc < 32; ++cc) v += s3[cc] * W4[cc * 21 + t];
        s4[t] = v;
    }
    __syncthreads();
    if (t < 36) out[b * 36 + t] = s4[c_IDX[t]];
}

// ================= fallback helpers (atomic path) =================
__global__ __launch_bounds__(256) void k_init_fb(const float* __restrict__ na,
                                                 const float* __restrict__ eW,
                                                 const float* __restrict__ eb,
                                                 float* __restrict__ x, unsigned short* __restrict__ xb,
                                                 float* __restrict__ agg) {
    int tid = blockIdx.x * 256 + threadIdx.x;
    int n = tid >> 5, c = tid & 31;
    float v = na[n] * eW[c] + eb[c];
    x[tid] = v;
    xb[tid] = f2bs(v);
    agg[tid] = 0.f;
}

__global__ __launch_bounds__(256) void k_prep_fb(const float* __restrict__ pos,
                                                 const float* __restrict__ shifts,
                                                 const float* __restrict__ eattr,
                                                 const int* __restrict__ eidx,
                                                 unsigned short* __restrict__ efp) {
    int e = blockIdx.x * 256 + threadIdx.x;
    int s = eidx[e], d = eidx[E_ + e];
    float vx = pos[d * 3 + 0] - pos[s * 3 + 0] + shifts[e * 3 + 0];
    float vy = pos[d * 3 + 1] - pos[s * 3 + 1] + shifts[e * 3 + 1];
    float vz = pos[d * 3 + 2] - pos[s * 3 + 2] + shifts[e * 3 + 2];
    float ln = sqrtf(vx * vx + vy * vy + vz * vz);
    u4 o;
    o[0] = pk2(vx, vy);
    o[1] = pk2(vz, ln);
    o[2] = pk2(eattr[e], 0.f);
    o[3] = 0u;
    *(u4*)(efp + (size_t)e * 8) = o;
}

__global__ __launch_bounds__(256) void k_repack_fb(const float* __restrict__ w3,
                                                   unsigned short* __restrict__ w3r,
                                                   const float* __restrict__ w1,
                                                   const float* __restrict__ w2,
                                                   unsigned short* __restrict__ w1r,
                                                   unsigned short* __restrict__ w2r) {
    int tid = blockIdx.x * 256 + threadIdx.x;
    if (tid < 12288) {
        int l = tid & 63, t2 = (tid >> 6) & 63, i = tid >> 12;
        int q = l >> 4, m = l & 15;
        U8 o;
        for (int j = 0; j < 8; ++j) {
            int k = q * 8 + j;
            o.us[j] = f2bs(w3[(i * 32 + k) * 1024 + t2 * 16 + m]);
        }
        *(u4*)(w3r + (size_t)tid * 8) = o.u;
    } else if (tid < 13056) {
        int t2 = tid - 12288;
        bool isw2 = t2 >= 384;
        int idx = isw2 ? t2 - 384 : t2;
        int i = idx >> 7, tau = (idx >> 6) & 1, l = idx & 63;
        int q = l >> 4, m = l & 15;
        U8 o;
        for (int j = 0; j < 8; ++j) {
            int k = q * 8 + j;
            if (!isw2) o.us[j] = (k < 5) ? f2bs(w1[i * 160 + k * 32 + tau * 16 + m]) : (unsigned short)0;
            else       o.us[j] = f2bs(w2[i * 1024 + k * 32 + tau * 16 + m]);
        }
        unsigned short* dst = (isw2 ? w2r : w1r) + i * 1024 + tau * 512 + l * 8;
        *(u4*)dst = o.u;
    }
}

__global__ __launch_bounds__(256) void k_node(float* __restrict__ x, unsigned short* __restrict__ xb,
                                              float* __restrict__ agg, const float* __restrict__ cb) {
    int tid = blockIdx.x * 256 + threadIdx.x;
    int c = tid & 31;
    float a = agg[tid] + cb[c];
    float v = x[tid] + fmaxf(a, 0.f);
    x[tid] = v;
    xb[tid] = f2bs(v);
    agg[tid] = 0.f;
}

__global__ __launch_bounds__(256) void k_zero_pool(float* __restrict__ pooled, int* __restrict__ cnt) {
    int tid = blockIdx.x * 256 + threadIdx.x;
    if (tid < 2048) pooled[tid] = 0.f;
    else if (tid < 2112) cnt[tid - 2048] = 0;
}

__global__ __launch_bounds__(256) void k_pool(const float* __restrict__ x, const int* __restrict__ batch,
                                              float* __restrict__ pooled, int* __restrict__ cnt) {
    int tid = blockIdx.x * 256 + threadIdx.x;
    int n = tid >> 5, c = tid & 31;
    int b = batch[n];
    atomicAdd(&pooled[b * 32 + c], x[tid]);
    if (c == 0) atomicAdd(&cnt[b], 1);
}

__global__ __launch_bounds__(128) void k_head(const float* __restrict__ pooled, const int* __restrict__ cnt,
                                              const float* __restrict__ W1, const float* __restrict__ b1,
                                              const float* __restrict__ W2, const float* __restrict__ b2,
                                              const float* __restrict__ W3, const float* __restrict__ b3,
                                              const float* __restrict__ W4, const float* __restrict__ b4,
                                              float* __restrict__ out) {
    __shared__ float s0[32], s1[128], s2[64], s3[32], s4[21];
    int b = blockIdx.x, t = threadIdx.x;
    if (t < 32) s0[t] = pooled[b * 32 + t] / fmaxf((float)cnt[b], 1.f);
    __syncthreads();
    {
        float a = b1[t];
        for (int c = 0; c < 32; ++c) a += s0[c] * W1[c * 128 + t];
        s1[t] = selu_(a);
    }
    __syncthreads();
    if (t < 64) {
        float a = b2[t];
        for (int c = 0; c < 128; ++c) a += s1[c] * W2[c * 64 + t];
        s2[t] = selu_(a);
    }
    __syncthreads();
    if (t < 32) {
        float a = b3[t];
        for (int c = 0; c < 64; ++c) a += s2[c] * W3[c * 32 + t];
        s3[t] = selu_(a);
    }
    __syncthreads();
    if (t < 21) {
        float a = b4[t];
        for (int c = 0; c < 32; ++c) a += s3[c] * W4[c * 21 + t];
        s4[t] = a;
    }
    __syncthreads();
    if (t < 36) out[b * 36 + t] = s4[c_IDX[t]];
}

extern "C" void kernel_launch(void* const* d_in, const int* in_sizes, int n_in,
                              void* d_out, int out_size, void* d_ws, size_t ws_size,
                              hipStream_t stream) {
    const float* na     = (const float*)d_in[0];
    const float* pos    = (const float*)d_in[1];
    const float* shifts = (const float*)d_in[2];
    const float* eattr  = (const float*)d_in[3];
    const int*   eidx   = (const int*)d_in[4];
    const int*   batch  = (const int*)d_in[5];
    const float* embW   = (const float*)d_in[6];
    const float* embB   = (const float*)d_in[7];
    const float* eW1    = (const float*)d_in[8];
    const float* eb1    = (const float*)d_in[9];
    const float* eW2    = (const float*)d_in[10];
    const float* eb2    = (const float*)d_in[11];
    const float* eW3    = (const float*)d_in[12];
    const float* eb3    = (const float*)d_in[13];
    const float* cvb    = (const float*)d_in[14];
    const float* hW1    = (const float*)d_in[15];
    const float* hb1    = (const float*)d_in[16];
    const float* hW2    = (const float*)d_in[17];
    const float* hb2    = (const float*)d_in[18];
    const float* hW3    = (const float*)d_in[19];
    const float* hb3    = (const float*)d_in[20];
    const float* hW4    = (const float*)d_in[21];
    const float* hb4    = (const float*)d_in[22];

    // layout: x | xb | deg | bcnt | off | cur | rank | boff | bcur | bperm | efp | w3r | w1r | w2r | msg
    const size_t need_csr = (size_t)640000 * 4 + (size_t)640000 * 2
                          + (size_t)(20000 + 64 + 20004 + 20000 + 320000 + 68 + 64 + 20000) * 4
                          + ((size_t)E_ * 8 + 98304 + 3072 + 3072 + (size_t)E_ * 32) * 2;

    if (ws_size >= need_csr) {
        char* ws = (char*)d_ws;
        float* x            = (float*)ws;                        // 640000 f32
        unsigned short* xb  = (unsigned short*)(x + 640000);     // 640000 bf16
        int*   deg    = (int*)(xb + 640000);                     // 20000
        int*   bcnt   = deg + 20000;                             // 64 (contiguous with deg)
        int*   off    = bcnt + 64;                               // 20001 (pad 20004)
        int*   cur    = off + 20004;                             // 20000
        int*   rank   = cur + 20000;                             // 320000
        int*   boff   = rank + 320000;                           // 65 (pad 68)
        int*   bcur   = boff + 68;                               // 64
        int*   bperm  = bcur + 64;                               // 20000
        unsigned short* efp = (unsigned short*)(bperm + 20000);  // E_*8 bf16
        unsigned short* w3r = efp + (size_t)E_ * 8;              // 98304 bf16
        unsigned short* w1r = w3r + 98304;                       // 3072 bf16
        unsigned short* w2r = w1r + 3072;                        // 3072 bf16
        unsigned short* msg = w2r + 3072;                        // E_*32 bf16

        hipMemsetAsync(deg, 0, (20000 + 64) * sizeof(int), stream);  // deg + bcnt
        k_setup<<<2005, 256, 0, stream>>>(na, embW, embB, x, xb, deg, bcnt,
                                          pos, shifts, eattr, eidx, efp,
                                          eW3, w3r, eW1, eW2, w1r, w2r, batch);
        k_scans<<<2, 1024, 0, stream>>>(deg, off, cur, bcnt, boff, bcur);
        k_fills<<<1329, 256, 0, stream>>>(eidx, cur, rank, batch, bcur, bperm);

        for (int i = 0; i < 3; ++i) {
            k_edge<true><<<1250, 256, 0, stream>>>(efp, eidx, rank, xb, nullptr, msg,
                                                   w1r + i * 1024, eb1 + i * 32,
                                                   w2r + i * 1024, eb2 + i * 32,
                                                   w3r + i * 32768, eb3 + i * 1024);
            k_gather<<<5000, 256, 0, stream>>>(msg, off, cvb + i * 32, x, xb);
        }

        k_pool_head<<<64, 1024, 0, stream>>>(x, boff, bperm,
                                             hW1, hb1, hW2, hb2, hW3, hb3, hW4, hb4,
                                             (float*)d_out);
    } else {
        // fallback: atomic scatter path
        char* ws = (char*)d_ws;
        float* x           = (float*)ws;                      // 640000 f32
        unsigned short* xb = (unsigned short*)(x + 640000);   // 640000 bf16
        float* agg    = (float*)(xb + 640000);                // 640000 f32
        float* pooled = agg + 640000;                         // 2048 f32
        int*   cnt    = (int*)(pooled + 2048);                // 64
        unsigned short* efp = (unsigned short*)(cnt + 64);    // E_*8 bf16
        unsigned short* w3r = efp + (size_t)E_ * 8;           // 98304 bf16
        unsigned short* w1r = w3r + 98304;                    // 3072
        unsigned short* w2r = w1r + 3072;                     // 3072

        k_init_fb<<<2500, 256, 0, stream>>>(na, embW, embB, x, xb, agg);
        k_prep_fb<<<1250, 256, 0, stream>>>(pos, shifts, eattr, eidx, efp);
        k_repack_fb<<<51, 256, 0, stream>>>(eW3, w3r, eW1, eW2, w1r, w2r);
        k_zero_pool<<<9, 256, 0, stream>>>(pooled, cnt);

        for (int i = 0; i < 3; ++i) {
            k_edge<false><<<1250, 256, 0, stream>>>(efp, eidx, nullptr, xb, agg, nullptr,
                                                    w1r + i * 1024, eb1 + i * 32,
                                                    w2r + i * 1024, eb2 + i * 32,
                                                    w3r + i * 32768, eb3 + i * 1024);
            k_node<<<2500, 256, 0, stream>>>(x, xb, agg, cvb + i * 32);
        }

        k_pool<<<2500, 256, 0, stream>>>(x, batch, pooled, cnt);
        k_head<<<64, 128, 0, stream>>>(pooled, cnt, hW1, hb1, hW2, hb2, hW3, hb3, hW4, hb4,
                                       (float*)d_out);
    }
}

// Round 17
// 344.133 us; speedup vs baseline: 1.2097x; 1.0509x over previous
//
#include <hip/hip_runtime.h>
#include <hip/hip_bf16.h>

#define N_ 20000
#define E_ 320000
#define B_ 64

typedef __attribute__((ext_vector_type(8))) short short8;
typedef __attribute__((ext_vector_type(4))) float f4;
typedef __attribute__((ext_vector_type(2))) float f2v;
typedef __attribute__((ext_vector_type(4))) unsigned int u4;
typedef __attribute__((ext_vector_type(4))) unsigned short us4;

union U8 { short s[8]; unsigned short us[8]; short8 v; u4 u; };
union F4 { f4 v; f2v h[2]; float f[4]; };

__device__ __forceinline__ float bs2f(unsigned short s) {
    return __uint_as_float(((unsigned int)s) << 16);
}
__device__ __forceinline__ unsigned short f2bs(float f) {
    unsigned int u = __float_as_uint(f);
    unsigned int r = u + 0x7FFFu + ((u >> 16) & 1u);  // round-to-nearest-even
    return (unsigned short)(r >> 16);
}
// packed f32x2 -> bf16x2 (v_cvt_pk_bf16_f32 on gfx950), low short = a
__device__ __forceinline__ unsigned int pk2(float a, float b) {
    __hip_bfloat162 h = __float22bfloat162_rn(make_float2(a, b));
    union { __hip_bfloat162 h2; unsigned int u; } cv;
    cv.h2 = h;
    return cv.u;
}

// wave-local LDS drain: s_h/s_x are per-wave buffers, no block barrier needed
#define WAVE_LDS_WAIT() asm volatile("s_waitcnt lgkmcnt(0)" ::: "memory")

#define MFMA_B16(a, b, c) __builtin_amdgcn_mfma_f32_16x16x32_bf16(a, b, c, 0, 0, 0)

__device__ __constant__ int c_IDX[36] = {
    0,1,2,3,4,5, 1,6,7,8,9,10, 2,7,11,12,13,14,
    3,8,12,15,16,17, 4,9,13,16,18,19, 5,10,14,17,19,20};

// ====== fused setup: init x/xb (f4) | edge_prep + deg hist + local rank | repack w3 | w1/w2 | batch hist ======
// deg/bcnt must be zeroed (hipMemsetAsync) BEFORE this kernel.
__global__ __launch_bounds__(256) void k_setup(
    const float* __restrict__ na, const float* __restrict__ eW, const float* __restrict__ eb,
    float* __restrict__ x, unsigned short* __restrict__ xb,
    int* __restrict__ deg, int* __restrict__ bcnt,
    const float* __restrict__ pos, const float* __restrict__ shifts, const float* __restrict__ eattr,
    const int* __restrict__ eidx, unsigned short* __restrict__ efp,
    const float* __restrict__ w3, unsigned short* __restrict__ w3r,
    const float* __restrict__ w1, const float* __restrict__ w2,
    unsigned short* __restrict__ w1r, unsigned short* __restrict__ w2r,
    const int* __restrict__ batch, int* __restrict__ rank) {
    int bid = blockIdx.x, t = threadIdx.x;
    if (bid < 625) {
        int tid = bid * 256 + t;          // < 160000 exact
        int base = tid * 4;
        int n = tid >> 3, c = (tid & 7) * 4;
        float nv = na[n];
        F4 o;
        for (int r = 0; r < 4; ++r) o.f[r] = nv * eW[c + r] + eb[c + r];
        *(f4*)(x + base) = o.v;
        uint2 pb;
        pb.x = pk2(o.f[0], o.f[1]);
        pb.y = pk2(o.f[2], o.f[3]);
        *(uint2*)(xb + base) = pb;
    } else if (bid < 1875) {
        int e = (bid - 625) * 256 + t;    // < E_ exact
        int s = eidx[e], d = eidx[E_ + e];
        float vx = pos[d * 3 + 0] - pos[s * 3 + 0] + shifts[e * 3 + 0];
        float vy = pos[d * 3 + 1] - pos[s * 3 + 1] + shifts[e * 3 + 1];
        float vz = pos[d * 3 + 2] - pos[s * 3 + 2] + shifts[e * 3 + 2];
        float ln = sqrtf(vx * vx + vy * vy + vz * vz);
        u4 o;
        o[0] = pk2(vx, vy);
        o[1] = pk2(vz, ln);
        o[2] = pk2(eattr[e], 0.f);
        o[3] = 0u;
        *(u4*)(efp + (size_t)e * 8) = o;
        rank[e] = atomicAdd(&deg[d], 1);  // histogram + local rank in one atomic
    } else if (bid < 1923) {
        int tid = (bid - 1875) * 256 + t; // < 12288 exact
        int l = tid & 63, t2 = (tid >> 6) & 63, i = tid >> 12;
        int q = l >> 4, m = l & 15;
        U8 o;
        for (int j = 0; j < 8; ++j) {
            int k = q * 8 + j;
            o.us[j] = f2bs(w3[(i * 32 + k) * 1024 + t2 * 16 + m]);
        }
        *(u4*)(w3r + (size_t)tid * 8) = o.u;
    } else if (bid < 1926) {
        int tid = (bid - 1923) * 256 + t; // < 768 exact
        bool isw2 = tid >= 384;
        int idx = isw2 ? tid - 384 : tid;
        int i = idx >> 7;                 // layer
        int tau = (idx >> 6) & 1;
        int l = idx & 63;
        int q = l >> 4, m = l & 15;
        U8 o;
        for (int j = 0; j < 8; ++j) {
            int k = q * 8 + j;
            if (!isw2) o.us[j] = (k < 5) ? f2bs(w1[i * 160 + k * 32 + tau * 16 + m]) : (unsigned short)0;
            else       o.us[j] = f2bs(w2[i * 1024 + k * 32 + tau * 16 + m]);
        }
        unsigned short* dst = (isw2 ? w2r : w1r) + i * 1024 + tau * 512 + l * 8;
        *(u4*)dst = o.u;
    } else {
        __shared__ int s[64];
        if (t < 64) s[t] = 0;
        __syncthreads();
        int n = (bid - 1926) * 256 + t;
        if (n < N_) atomicAdd(&s[batch[n]], 1);
        __syncthreads();
        if (t < 64 && s[t]) atomicAdd(&bcnt[t], s[t]);
    }
}

// ================= fused scans (shfl-based, 2 barriers) =================
__global__ __launch_bounds__(1024) void k_scans(const int* __restrict__ deg,
                                                int* __restrict__ off,
                                                const int* __restrict__ bcnt,
                                                int* __restrict__ boff, int* __restrict__ bcur) {
    int t = threadIdx.x;
    if (blockIdx.x == 0) {
        __shared__ int shW[16];
        int base = t * 20;  // 1024*20 >= N_
        int loc[20]; int s = 0;
        for (int k = 0; k < 20; ++k) {
            int i = base + k;
            int v = (i < N_) ? deg[i] : 0;
            loc[k] = s; s += v;
        }
        int lane = t & 63, wv = t >> 6;
        int v = s;
        for (int d = 1; d < 64; d <<= 1) {
            int u = __shfl_up(v, d);
            if (lane >= d) v += u;
        }
        if (lane == 63) shW[wv] = v;
        __syncthreads();
        if (wv == 0) {
            int w = (lane < 16) ? shW[lane] : 0;
            for (int d = 1; d < 16; d <<= 1) {
                int u = __shfl_up(w, d);
                if (lane >= d) w += u;
            }
            if (lane < 16) shW[lane] = w;
        }
        __syncthreads();
        int woff = (wv > 0) ? shW[wv - 1] : 0;
        int incl = v + woff;
        int excl = incl - s;
        for (int k = 0; k < 20; ++k) {
            int i = base + k;
            if (i < N_) off[i] = excl + loc[k];
        }
        if (t == 1023) off[N_] = incl;
    } else {
        if (t < 64) {
            int v0 = bcnt[t];
            int v = v0;
            for (int d = 1; d < 64; d <<= 1) {
                int u = __shfl_up(v, d);
                if (t >= d) v += u;
            }
            boff[t] = v - v0; bcur[t] = v - v0;
            if (t == 63) boff[64] = v;
        }
    }
}

// ================= fused fills: rank[e] += off[dst] (streaming, no atomics) + bperm =================
__global__ __launch_bounds__(256) void k_fills(const int* __restrict__ eidx,
                                               const int* __restrict__ off, int* __restrict__ rank,
                                               const int* __restrict__ batch,
                                               int* __restrict__ bcur, int* __restrict__ bperm) {
    int bid = blockIdx.x, t = threadIdx.x;
    if (bid < 1250) {
        int e = bid * 256 + t;
        rank[e] += off[eidx[E_ + e]];
    } else {
        int n = (bid - 1250) * 256 + t;
        if (n < N_) {
            int p = atomicAdd(&bcur[batch[n]], 1);
            bperm[p] = n;
        }
    }
}

// ================= main edge kernel: 64 edges/wave, rank-order msg stores (R12-proven) =================
template <bool STORE>
__global__ __launch_bounds__(256, 5) void k_edge(
    const unsigned short* __restrict__ efp, const int* __restrict__ eidx,
    const int* __restrict__ rank,
    const unsigned short* __restrict__ xb, float* __restrict__ agg, unsigned short* __restrict__ msg,
    const unsigned short* __restrict__ w1r, const float* __restrict__ b1,
    const unsigned short* __restrict__ w2r, const float* __restrict__ b2,
    const unsigned short* __restrict__ w3r, const float* __restrict__ b3) {
    __shared__ float s_b3[1024];                            // 4 KB (block-shared)
    __shared__ __align__(16) unsigned short s_h[4][640];    // per-wave transpose buf, stride 40
    __shared__ __align__(16) unsigned short s_x[4][4][640]; // per-wave bf16 x tiles, stride 40

    const int t = threadIdx.x;
    for (int k = t; k < 1024; k += 256) s_b3[k] = b3[k];

    const int wave = t >> 6, lane = t & 63;
    const int q = lane >> 4, e = lane & 15;
    const int ebase = (blockIdx.x * 4 + wave) * 64;

    // stage x[src] tiles from bf16 mirror: one u4 (16B) load + one 16B LDS store per lane
    for (int g = 0; g < 4; ++g) {
        int srce = eidx[ebase + g * 16 + e];
        u4 P = *(const u4*)(xb + srce * 32 + q * 8);
        *(u4*)&s_x[wave][g][e * 40 + q * 8] = P;  // byte offset e*80+q*16, 16B-aligned
    }

    // loop-invariant W1^T / W2^T fragments (pre-repacked) + bias regs
    U8 w1f[2], w2f[2];
    float b1v[2][4], b2v[2][4];
    for (int tau = 0; tau < 2; ++tau) {
        w1f[tau].u = *(const u4*)(w1r + tau * 512 + lane * 8);
        w2f[tau].u = *(const u4*)(w2r + tau * 512 + lane * 8);
        for (int r = 0; r < 4; ++r) {
            b1v[tau][r] = b1[tau * 16 + q * 4 + r];
            b2v[tau][r] = b2[tau * 16 + q * 4 + r];
        }
    }

    const f4 z4 = {0.f, 0.f, 0.f, 0.f};
    const f2v z2 = {0.f, 0.f};
    short8 h2f[4];

    // per-g MLP: within-wave LDS traffic only -> wave-local waits
    for (int g = 0; g < 4; ++g) {
        U8 ef;
        if (q == 0) ef.u = *(const u4*)(efp + (size_t)(ebase + g * 16 + e) * 8);
        else { u4 zz = {0u, 0u, 0u, 0u}; ef.u = zz; }

        f4 c0 = MFMA_B16(w1f[0].v, ef.v, z4);
        f4 c1 = MFMA_B16(w1f[1].v, ef.v, z4);
        uint2 pkw;
        pkw.x = pk2(fmaxf(c0[0] + b1v[0][0], 0.f), fmaxf(c0[1] + b1v[0][1], 0.f));
        pkw.y = pk2(fmaxf(c0[2] + b1v[0][2], 0.f), fmaxf(c0[3] + b1v[0][3], 0.f));
        *(uint2*)&s_h[wave][e * 40 + q * 4] = pkw;
        pkw.x = pk2(fmaxf(c1[0] + b1v[1][0], 0.f), fmaxf(c1[1] + b1v[1][1], 0.f));
        pkw.y = pk2(fmaxf(c1[2] + b1v[1][2], 0.f), fmaxf(c1[3] + b1v[1][3], 0.f));
        *(uint2*)&s_h[wave][e * 40 + 16 + q * 4] = pkw;
        WAVE_LDS_WAIT();
        short8 h1f = *(const short8*)&s_h[wave][e * 40 + q * 8];
        c0 = MFMA_B16(w2f[0].v, h1f, z4);
        c1 = MFMA_B16(w2f[1].v, h1f, z4);
        pkw.x = pk2(fmaxf(c0[0] + b2v[0][0], 0.f), fmaxf(c0[1] + b2v[0][1], 0.f));
        pkw.y = pk2(fmaxf(c0[2] + b2v[0][2], 0.f), fmaxf(c0[3] + b2v[0][3], 0.f));
        *(uint2*)&s_h[wave][e * 40 + q * 4] = pkw;
        pkw.x = pk2(fmaxf(c1[0] + b2v[1][0], 0.f), fmaxf(c1[1] + b2v[1][1], 0.f));
        pkw.y = pk2(fmaxf(c1[2] + b2v[1][2], 0.f), fmaxf(c1[3] + b2v[1][3], 0.f));
        *(uint2*)&s_h[wave][e * 40 + 16 + q * 4] = pkw;
        WAVE_LDS_WAIT();
        h2f[g] = *(const short8*)&s_h[wave][e * 40 + q * 8];
        WAVE_LDS_WAIT();
    }

    __syncthreads();  // s_b3 visibility

    F4 macc[4][2];
    for (int g = 0; g < 4; ++g) { macc[g][0].v = z4; macc[g][1].v = z4; }

#pragma unroll 4
    for (int h = 0; h < 32; ++h) {
        short8 a0 = *(const short8*)(w3r + h * 1024 + lane * 8);
        short8 a1 = *(const short8*)(w3r + h * 1024 + 512 + lane * 8);
        f4 ci0 = *(const f4*)&s_b3[h * 32 + q * 4];
        f4 ci1 = *(const f4*)&s_b3[h * 32 + 16 + q * 4];
        for (int g = 0; g < 4; ++g) {
            float xv = bs2f(s_x[wave][g][e * 40 + h]);
            F4 d0, d1, m0, m1;
            d0.v = MFMA_B16(a0, h2f[g], ci0);
            d1.v = MFMA_B16(a1, h2f[g], ci1);
            m0.h[0] = __builtin_elementwise_max(d0.h[0], z2);   // v_pk_max_f32
            m0.h[1] = __builtin_elementwise_max(d0.h[1], z2);
            m1.h[0] = __builtin_elementwise_max(d1.h[0], z2);
            m1.h[1] = __builtin_elementwise_max(d1.h[1], z2);
            f2v xv2 = {xv, xv};
            macc[g][0].h[0] = __builtin_elementwise_fma(m0.h[0], xv2, macc[g][0].h[0]);
            macc[g][0].h[1] = __builtin_elementwise_fma(m0.h[1], xv2, macc[g][0].h[1]);
            macc[g][1].h[0] = __builtin_elementwise_fma(m1.h[0], xv2, macc[g][1].h[0]);
            macc[g][1].h[1] = __builtin_elementwise_fma(m1.h[1], xv2, macc[g][1].h[1]);
        }
    }

    if (STORE) {
        for (int g = 0; g < 4; ++g) {
            int rk = rank[ebase + g * 16 + e];
            unsigned short* mp = msg + (size_t)rk * 32 + q * 4;
            for (int p = 0; p < 2; ++p) {
                uint2 m;
                m.x = pk2(macc[g][p].f[0], macc[g][p].f[1]);
                m.y = pk2(macc[g][p].f[2], macc[g][p].f[3]);
                *(uint2*)(mp + p * 16) = m;
            }
        }
    } else {
        for (int g = 0; g < 4; ++g) {
            int dste = eidx[E_ + ebase + g * 16 + e];
            float* ap = agg + dste * 32 + q * 4;
            for (int p = 0; p < 2; ++p)
                for (int r = 0; r < 4; ++r)
                    atomicAdd(ap + p * 16 + r, macc[g][p].f[r]);
        }
    }
}

// ================= gather: one wave per node, contiguous u4 streaming; maintains xb =================
__global__ __launch_bounds__(256) void k_gather(const unsigned short* __restrict__ msg,
                                                const int* __restrict__ off,
                                                const float* __restrict__ cb,
                                                float* __restrict__ x,
                                                unsigned short* __restrict__ xb) {
    int wave = threadIdx.x >> 6, lane = threadIdx.x & 63;
    int n = blockIdx.x * 4 + wave;
    if (n >= N_) return;
    int j0 = off[n], j1 = off[n + 1];
    const unsigned short* base = msg + (size_t)j0 * 32;
    int nchunk = (j1 - j0) * 4;  // 16B chunks; row=64B so always whole chunks
    float a[8] = {0.f, 0.f, 0.f, 0.f, 0.f, 0.f, 0.f, 0.f};
    for (int it = lane; it < nchunk; it += 64) {
        u4 v = *(const u4*)(base + it * 8);
        for (int m = 0; m < 4; ++m) {
            unsigned int w = v[m];
            a[2 * m]     += __uint_as_float(w << 16);
            a[2 * m + 1] += __uint_as_float(w & 0xffff0000u);
        }
    }
    for (int d = 4; d < 64; d <<= 1)
        for (int m = 0; m < 8; ++m)
            a[m] += __shfl_xor(a[m], d);
    if (lane < 4) {
        int c0 = lane * 8;
        float* xp = x + n * 32 + c0;
        F4 xa, xb2;
        xa.v = *(const f4*)xp;
        xb2.v = *(const f4*)(xp + 4);
        for (int i = 0; i < 4; ++i) {
            xa.f[i]  += fmaxf(a[i] + cb[c0 + i], 0.f);
            xb2.f[i] += fmaxf(a[4 + i] + cb[c0 + 4 + i], 0.f);
        }
        *(f4*)xp = xa.v;
        *(f4*)(xp + 4) = xb2.v;
        u4 P;
        P[0] = pk2(xa.f[0], xa.f[1]);
        P[1] = pk2(xa.f[2], xa.f[3]);
        P[2] = pk2(xb2.f[0], xb2.f[1]);
        P[3] = pk2(xb2.f[2], xb2.f[3]);
        *(u4*)(xb + n * 32 + c0) = P;
    }
}

__device__ __forceinline__ float selu_(float v) {
    return 1.0507009873554805f * (v > 0.f ? v : 1.6732632423543772f * (expf(v) - 1.f));
}

// ================= fused pooling (32 slots) + head MLP + IDX gather =================
__global__ __launch_bounds__(1024) void k_pool_head(const float* __restrict__ x,
                                                    const int* __restrict__ boff,
                                                    const int* __restrict__ bperm,
                                                    const float* __restrict__ W1, const float* __restrict__ b1,
                                                    const float* __restrict__ W2, const float* __restrict__ b2,
                                                    const float* __restrict__ W3, const float* __restrict__ b3,
                                                    const float* __restrict__ W4, const float* __restrict__ b4,
                                                    float* __restrict__ out) {
    __shared__ float sp[32][32];
    __shared__ float s0[32], s1[128], s2[64], s3[32], s4[21];
    int b = blockIdx.x, t = threadIdx.x, c = t & 31, slot = t >> 5;
    int j0 = boff[b], j1 = boff[b + 1];
    float a = 0.f;
    for (int j = j0 + slot; j < j1; j += 32)
        a += x[bperm[j] * 32 + c];
    sp[slot][c] = a;
    __syncthreads();
    if (t < 32) {
        float s = 0.f;
        for (int k = 0; k < 32; ++k) s += sp[k][t];
        s0[t] = s / fmaxf((float)(j1 - j0), 1.f);
    }
    __syncthreads();
    if (t < 128) {
        float v = b1[t];
        for (int cc = 0; cc < 32; ++cc) v += s0[cc] * W1[cc * 128 + t];
        s1[t] = selu_(v);
    }
    __syncthreads();
    if (t < 64) {
        float v = b2[t];
        for (int cc = 0; cc < 128; ++cc) v += s1[cc] * W2[cc * 64 + t];
        s2[t] = selu_(v);
    }
    __syncthreads();
    if (t < 32) {
        float v = b3[t];
        for (int cc = 0; cc < 64; ++cc) v += s2[cc] * W3[cc * 32 + t];
        s3[t] = selu_(v);
    }
    __syncthreads();
    if (t < 21) {
        float v = b4[t];
        for (int cc = 0; cc < 32; ++cc) v += s3[cc] * W4[cc * 21 + t];
        s4[t] = v;
    }
    __syncthreads();
    if (t < 36) out[b * 36 + t] = s4[c_IDX[t]];
}

// ================= fallback helpers (atomic path) =================
__global__ __launch_bounds__(256) void k_init_fb(const float* __restrict__ na,
                                                 const float* __restrict__ eW,
                                                 const float* __restrict__ eb,
                                                 float* __restrict__ x, unsigned short* __restrict__ xb,
                                                 float* __restrict__ agg) {
    int tid = blockIdx.x * 256 + threadIdx.x;
    int n = tid >> 5, c = tid & 31;
    float v = na[n] * eW[c] + eb[c];
    x[tid] = v;
    xb[tid] = f2bs(v);
    agg[tid] = 0.f;
}

__global__ __launch_bounds__(256) void k_prep_fb(const float* __restrict__ pos,
                                                 const float* __restrict__ shifts,
                                                 const float* __restrict__ eattr,
                                                 const int* __restrict__ eidx,
                                                 unsigned short* __restrict__ efp) {
    int e = blockIdx.x * 256 + threadIdx.x;
    int s = eidx[e], d = eidx[E_ + e];
    float vx = pos[d * 3 + 0] - pos[s * 3 + 0] + shifts[e * 3 + 0];
    float vy = pos[d * 3 + 1] - pos[s * 3 + 1] + shifts[e * 3 + 1];
    float vz = pos[d * 3 + 2] - pos[s * 3 + 2] + shifts[e * 3 + 2];
    float ln = sqrtf(vx * vx + vy * vy + vz * vz);
    u4 o;
    o[0] = pk2(vx, vy);
    o[1] = pk2(vz, ln);
    o[2] = pk2(eattr[e], 0.f);
    o[3] = 0u;
    *(u4*)(efp + (size_t)e * 8) = o;
}

__global__ __launch_bounds__(256) void k_repack_fb(const float* __restrict__ w3,
                                                   unsigned short* __restrict__ w3r,
                                                   const float* __restrict__ w1,
                                                   const float* __restrict__ w2,
                                                   unsigned short* __restrict__ w1r,
                                                   unsigned short* __restrict__ w2r) {
    int tid = blockIdx.x * 256 + threadIdx.x;
    if (tid < 12288) {
        int l = tid & 63, t2 = (tid >> 6) & 63, i = tid >> 12;
        int q = l >> 4, m = l & 15;
        U8 o;
        for (int j = 0; j < 8; ++j) {
            int k = q * 8 + j;
            o.us[j] = f2bs(w3[(i * 32 + k) * 1024 + t2 * 16 + m]);
        }
        *(u4*)(w3r + (size_t)tid * 8) = o.u;
    } else if (tid < 13056) {
        int t2 = tid - 12288;
        bool isw2 = t2 >= 384;
        int idx = isw2 ? t2 - 384 : t2;
        int i = idx >> 7, tau = (idx >> 6) & 1, l = idx & 63;
        int q = l >> 4, m = l & 15;
        U8 o;
        for (int j = 0; j < 8; ++j) {
            int k = q * 8 + j;
            if (!isw2) o.us[j] = (k < 5) ? f2bs(w1[i * 160 + k * 32 + tau * 16 + m]) : (unsigned short)0;
            else       o.us[j] = f2bs(w2[i * 1024 + k * 32 + tau * 16 + m]);
        }
        unsigned short* dst = (isw2 ? w2r : w1r) + i * 1024 + tau * 512 + l * 8;
        *(u4*)dst = o.u;
    }
}

__global__ __launch_bounds__(256) void k_node(float* __restrict__ x, unsigned short* __restrict__ xb,
                                              float* __restrict__ agg, const float* __restrict__ cb) {
    int tid = blockIdx.x * 256 + threadIdx.x;
    int c = tid & 31;
    float a = agg[tid] + cb[c];
    float v = x[tid] + fmaxf(a, 0.f);
    x[tid] = v;
    xb[tid] = f2bs(v);
    agg[tid] = 0.f;
}

__global__ __launch_bounds__(256) void k_zero_pool(float* __restrict__ pooled, int* __restrict__ cnt) {
    int tid = blockIdx.x * 256 + threadIdx.x;
    if (tid < 2048) pooled[tid] = 0.f;
    else if (tid < 2112) cnt[tid - 2048] = 0;
}

__global__ __launch_bounds__(256) void k_pool(const float* __restrict__ x, const int* __restrict__ batch,
                                              float* __restrict__ pooled, int* __restrict__ cnt) {
    int tid = blockIdx.x * 256 + threadIdx.x;
    int n = tid >> 5, c = tid & 31;
    int b = batch[n];
    atomicAdd(&pooled[b * 32 + c], x[tid]);
    if (c == 0) atomicAdd(&cnt[b], 1);
}

__global__ __launch_bounds__(128) void k_head(const float* __restrict__ pooled, const int* __restrict__ cnt,
                                              const float* __restrict__ W1, const float* __restrict__ b1,
                                              const float* __restrict__ W2, const float* __restrict__ b2,
                                              const float* __restrict__ W3, const float* __restrict__ b3,
                                              const float* __restrict__ W4, const float* __restrict__ b4,
                                              float* __restrict__ out) {
    __shared__ float s0[32], s1[128], s2[64], s3[32], s4[21];
    int b = blockIdx.x, t = threadIdx.x;
    if (t < 32) s0[t] = pooled[b * 32 + t] / fmaxf((float)cnt[b], 1.f);
    __syncthreads();
    {
        float a = b1[t];
        for (int c = 0; c < 32; ++c) a += s0[c] * W1[c * 128 + t];
        s1[t] = selu_(a);
    }
    __syncthreads();
    if (t < 64) {
        float a = b2[t];
        for (int c = 0; c < 128; ++c) a += s1[c] * W2[c * 64 + t];
        s2[t] = selu_(a);
    }
    __syncthreads();
    if (t < 32) {
        float a = b3[t];
        for (int c = 0; c < 64; ++c) a += s2[c] * W3[c * 32 + t];
        s3[t] = selu_(a);
    }
    __syncthreads();
    if (t < 21) {
        float a = b4[t];
        for (int c = 0; c < 32; ++c) a += s3[c] * W4[c * 21 + t];
        s4[t] = a;
    }
    __syncthreads();
    if (t < 36) out[b * 36 + t] = s4[c_IDX[t]];
}

extern "C" void kernel_launch(void* const* d_in, const int* in_sizes, int n_in,
                              void* d_out, int out_size, void* d_ws, size_t ws_size,
                              hipStream_t stream) {
    const float* na     = (const float*)d_in[0];
    const float* pos    = (const float*)d_in[1];
    const float* shifts = (const float*)d_in[2];
    const float* eattr  = (const float*)d_in[3];
    const int*   eidx   = (const int*)d_in[4];
    const int*   batch  = (const int*)d_in[5];
    const float* embW   = (const float*)d_in[6];
    const float* embB   = (const float*)d_in[7];
    const float* eW1    = (const float*)d_in[8];
    const float* eb1    = (const float*)d_in[9];
    const float* eW2    = (const float*)d_in[10];
    const float* eb2    = (const float*)d_in[11];
    const float* eW3    = (const float*)d_in[12];
    const float* eb3    = (const float*)d_in[13];
    const float* cvb    = (const float*)d_in[14];
    const float* hW1    = (const float*)d_in[15];
    const float* hb1    = (const float*)d_in[16];
    const float* hW2    = (const float*)d_in[17];
    const float* hb2    = (const float*)d_in[18];
    const float* hW3    = (const float*)d_in[19];
    const float* hb3    = (const float*)d_in[20];
    const float* hW4    = (const float*)d_in[21];
    const float* hb4    = (const float*)d_in[22];

    // layout: x | xb | deg | bcnt | off | cur(unused) | rank | boff | bcur | bperm | efp | w3r | w1r | w2r | msg
    const size_t need_csr = (size_t)640000 * 4 + (size_t)640000 * 2
                          + (size_t)(20000 + 64 + 20004 + 20000 + 320000 + 68 + 64 + 20000) * 4
                          + ((size_t)E_ * 8 + 98304 + 3072 + 3072 + (size_t)E_ * 32) * 2;

    if (ws_size >= need_csr) {
        char* ws = (char*)d_ws;
        float* x            = (float*)ws;                        // 640000 f32
        unsigned short* xb  = (unsigned short*)(x + 640000);     // 640000 bf16
        int*   deg    = (int*)(xb + 640000);                     // 20000
        int*   bcnt   = deg + 20000;                             // 64 (contiguous with deg)
        int*   off    = bcnt + 64;                               // 20001 (pad 20004)
        int*   cur    = off + 20004;                             // 20000 (unused, kept for layout)
        int*   rank   = cur + 20000;                             // 320000
        int*   boff   = rank + 320000;                           // 65 (pad 68)
        int*   bcur   = boff + 68;                               // 64
        int*   bperm  = bcur + 64;                               // 20000
        unsigned short* efp = (unsigned short*)(bperm + 20000);  // E_*8 bf16
        unsigned short* w3r = efp + (size_t)E_ * 8;              // 98304 bf16
        unsigned short* w1r = w3r + 98304;                       // 3072 bf16
        unsigned short* w2r = w1r + 3072;                        // 3072 bf16
        unsigned short* msg = w2r + 3072;                        // E_*32 bf16

        hipMemsetAsync(deg, 0, (20000 + 64) * sizeof(int), stream);  // deg + bcnt
        k_setup<<<2005, 256, 0, stream>>>(na, embW, embB, x, xb, deg, bcnt,
                                          pos, shifts, eattr, eidx, efp,
                                          eW3, w3r, eW1, eW2, w1r, w2r, batch, rank);
        k_scans<<<2, 1024, 0, stream>>>(deg, off, bcnt, boff, bcur);
        k_fills<<<1329, 256, 0, stream>>>(eidx, off, rank, batch, bcur, bperm);

        for (int i = 0; i < 3; ++i) {
            k_edge<true><<<1250, 256, 0, stream>>>(efp, eidx, rank, xb, nullptr, msg,
                                                   w1r + i * 1024, eb1 + i * 32,
                                                   w2r + i * 1024, eb2 + i * 32,
                                                   w3r + i * 32768, eb3 + i * 1024);
            k_gather<<<5000, 256, 0, stream>>>(msg, off, cvb + i * 32, x, xb);
        }

        k_pool_head<<<64, 1024, 0, stream>>>(x, boff, bperm,
                                             hW1, hb1, hW2, hb2, hW3, hb3, hW4, hb4,
                                             (float*)d_out);
    } else {
        // fallback: atomic scatter path
        char* ws = (char*)d_ws;
        float* x           = (float*)ws;                      // 640000 f32
        unsigned short* xb = (unsigned short*)(x + 640000);   // 640000 bf16
        float* agg    = (float*)(xb + 640000);                // 640000 f32
        float* pooled = agg + 640000;                         // 2048 f32
        int*   cnt    = (int*)(pooled + 2048);                // 64
        unsigned short* efp = (unsigned short*)(cnt + 64);    // E_*8 bf16
        unsigned short* w3r = efp + (size_t)E_ * 8;           // 98304 bf16
        unsigned short* w1r = w3r + 98304;                    // 3072
        unsigned short* w2r = w1r + 3072;                     // 3072

        k_init_fb<<<2500, 256, 0, stream>>>(na, embW, embB, x, xb, agg);
        k_prep_fb<<<1250, 256, 0, stream>>>(pos, shifts, eattr, eidx, efp);
        k_repack_fb<<<51, 256, 0, stream>>>(eW3, w3r, eW1, eW2, w1r, w2r);
        k_zero_pool<<<9, 256, 0, stream>>>(pooled, cnt);

        for (int i = 0; i < 3; ++i) {
            k_edge<false><<<1250, 256, 0, stream>>>(efp, eidx, nullptr, xb, agg, nullptr,
                                                    w1r + i * 1024, eb1 + i * 32,
                                                    w2r + i * 1024, eb2 + i * 32,
                                                    w3r + i * 32768, eb3 + i * 1024);
            k_node<<<2500, 256, 0, stream>>>(x, xb, agg, cvb + i * 32);
        }

        k_pool<<<2500, 256, 0, stream>>>(x, batch, pooled, cnt);
        k_head<<<64, 128, 0, stream>>>(pooled, cnt, hW1, hb1, hW2, hb2, hW3, hb3, hW4, hb4,
                                       (float*)d_out);
    }
}